// Round 6
// baseline (267.496 us; speedup 1.0000x reference)
//
#include <hip/hip_runtime.h>

// Decay-based linear recurrent scan:  S_t = d*S_{t-1} + (1-d)*kv_t ; out_t = q_t*S_t
// fp32, (T,B,H,V,D) = (128,16,8,25,64).
//
// Round-8 design: two-pass chunked scan tuned for DRAM run length.
//   Evidence: retirement rate tracks per-t contiguous footprint per block:
//     1 KB runs -> 1.96 TB/s (v7), 2 KB -> 2.51 TB/s (v8), 4 KB -> ~4.2 TB/s
//     (round-1 two-pass, 256-thr blocks), sequential fill -> 6.8 TB/s.
//   TLP falsified (v7: occupancy 6.8%->31%, BW flat); per-wave MLP depth
//   compiler-inaccessible (v4/v6 collapsed, v5 crashed).
//   This version: 256 threads x CPT=4 chains, all waves of a block in the SAME
//   time-chunk -> 16 KB contiguous per array per t-visit. 8 chunks x 50 blocks
//   = 400 blocks/pass, 1600 waves, all CUs busy.
//   Pass 1: read kv once -> per-chunk contributions B_c to ws (6.5 MB).
//   Pass 2: S_in = Horner fold of B (A = d^16), then replay: kv re-read comes
//   from MALL (105 MB << 256 MB; NT out-stores keep it resident — round-0
//   FETCH showed exactly half of reads HBM-fetched with NT stores), q read
//   once, out NT-stored.
//   Numerics: identical chunk reassociation to rounds 1/4/5 (passed, 2e-3).

#define T_DIM 128
#define CH4   51200             // float4 channels = B*H*V*D/4
#define VD    1600              // V*D (scalars)
#define NC    8                 // time chunks
#define LCH   (T_DIM / NC)      // 16 steps per chunk
#define THR   256               // threads per block
#define CPT   4                 // channel-chains per thread
#define BCH   (THR * CPT)       // f4-channels per block = 1024 (16 KB span)
#define BPC   (CH4 / BCH)       // 50 blocks per chunk

typedef float f32x4 __attribute__((ext_vector_type(4)));

// ---------------------------------------------------------------- pass 1 ----
__global__ __launch_bounds__(THR) void sss_p1(
    const f32x4* __restrict__ kv,
    const float* __restrict__ decay,
    f32x4* __restrict__ ws)
{
    const int bid = blockIdx.x;
    const int c   = bid / BPC;                       // chunk (block-uniform)
    const int cb  = (bid % BPC) * BCH + threadIdx.x; // chain-0 f4-channel

    int ci[CPT];
    f32x4 d[CPT], omd[CPT], S[CPT];
    #pragma unroll
    for (int cc = 0; cc < CPT; ++cc) {
        ci[cc] = cb + cc * THR;
        const int e0 = ci[cc] * 4;
        d[cc]   = *(const f32x4*)(decay + ((e0 / VD) & 7) * 64 + (e0 & 63));
        omd[cc] = 1.0f - d[cc];
        S[cc]   = (f32x4)0.0f;
    }

    const size_t tb = (size_t)c * LCH;
    #pragma unroll
    for (int j = 0; j < LCH; ++j) {
        f32x4 k[CPT];
        #pragma unroll
        for (int cc = 0; cc < CPT; ++cc)          // 4x 1KB wave-loads, adjacent
            k[cc] = kv[(tb + j) * CH4 + ci[cc]];
        #pragma unroll
        for (int cc = 0; cc < CPT; ++cc) {
            S[cc][0] = fmaf(d[cc][0], S[cc][0], omd[cc][0] * k[cc][0]);
            S[cc][1] = fmaf(d[cc][1], S[cc][1], omd[cc][1] * k[cc][1]);
            S[cc][2] = fmaf(d[cc][2], S[cc][2], omd[cc][2] * k[cc][2]);
            S[cc][3] = fmaf(d[cc][3], S[cc][3], omd[cc][3] * k[cc][3]);
        }
    }
    #pragma unroll
    for (int cc = 0; cc < CPT; ++cc)
        ws[(size_t)c * CH4 + ci[cc]] = S[cc];
}

// ---------------------------------------------------------------- pass 2 ----
__global__ __launch_bounds__(THR) void sss_p2(
    const f32x4* __restrict__ q,
    const f32x4* __restrict__ kv,
    const float* __restrict__ decay,
    const f32x4* __restrict__ ws,
    f32x4* __restrict__ out)
{
    const int bid = blockIdx.x;
    const int c   = bid / BPC;
    const int cb  = (bid % BPC) * BCH + threadIdx.x;

    int ci[CPT];
    f32x4 d[CPT], omd[CPT], A[CPT], S[CPT];
    #pragma unroll
    for (int cc = 0; cc < CPT; ++cc) {
        ci[cc] = cb + cc * THR;
        const int e0 = ci[cc] * 4;
        d[cc]   = *(const f32x4*)(decay + ((e0 / VD) & 7) * 64 + (e0 & 63));
        omd[cc] = 1.0f - d[cc];
        f32x4 a = d[cc] * d[cc];  a = a * a;  a = a * a;  a = a * a;  // d^16
        A[cc] = a;
        S[cc] = (f32x4)0.0f;
    }

    // chunk-prefix fold: S_in = sum_{c'<c} A^(c-1-c') B_c'  (block-uniform trips)
    for (int cp = 0; cp < c; ++cp) {
        #pragma unroll
        for (int cc = 0; cc < CPT; ++cc) {
            const f32x4 B = ws[(size_t)cp * CH4 + ci[cc]];
            S[cc][0] = fmaf(A[cc][0], S[cc][0], B[0]);
            S[cc][1] = fmaf(A[cc][1], S[cc][1], B[1]);
            S[cc][2] = fmaf(A[cc][2], S[cc][2], B[2]);
            S[cc][3] = fmaf(A[cc][3], S[cc][3], B[3]);
        }
    }

    const size_t tb = (size_t)c * LCH;
    #pragma unroll
    for (int j = 0; j < LCH; ++j) {
        f32x4 k[CPT], qq[CPT];
        #pragma unroll
        for (int cc = 0; cc < CPT; ++cc)
            k[cc] = kv[(tb + j) * CH4 + ci[cc]];
        #pragma unroll
        for (int cc = 0; cc < CPT; ++cc)
            qq[cc] = q[(tb + j) * CH4 + ci[cc]];
        #pragma unroll
        for (int cc = 0; cc < CPT; ++cc) {
            S[cc][0] = fmaf(d[cc][0], S[cc][0], omd[cc][0] * k[cc][0]);
            S[cc][1] = fmaf(d[cc][1], S[cc][1], omd[cc][1] * k[cc][1]);
            S[cc][2] = fmaf(d[cc][2], S[cc][2], omd[cc][2] * k[cc][2]);
            S[cc][3] = fmaf(d[cc][3], S[cc][3], omd[cc][3] * k[cc][3]);
            f32x4 o = qq[cc] * S[cc];
            __builtin_nontemporal_store(o, out + (tb + j) * CH4 + ci[cc]);
        }
    }
}

// ---------------------- fallback: single-kernel chunked scan (round-4, passed)
#define NW    8
__global__ __launch_bounds__(NW * 64) void sss_scan_v7(
    const f32x4* __restrict__ q,
    const f32x4* __restrict__ kv,
    const float* __restrict__ decay,
    f32x4* __restrict__ out)
{
    __shared__ f32x4 Blds[NW][64];
    const int w    = threadIdx.x >> 6;
    const int lane = threadIdx.x & 63;
    const int ci   = blockIdx.x * 64 + lane;
    const int e0   = ci * 4;
    const f32x4 d   = *(const f32x4*)(decay + ((e0 / VD) & 7) * 64 + (e0 & 63));
    const f32x4 omd = 1.0f - d;
    const size_t tbase = (size_t)w * (T_DIM / NW);
    const f32x4* kp = kv  + tbase * CH4 + ci;
    const f32x4* qp = q   + tbase * CH4 + ci;
    f32x4*       op = out + tbase * CH4 + ci;
    f32x4 B = (f32x4)0.0f;
    #pragma unroll
    for (int j = 0; j < T_DIM / NW; ++j) {
        f32x4 k = kp[(size_t)j * CH4];
        B[0] = fmaf(d[0], B[0], omd[0] * k[0]);
        B[1] = fmaf(d[1], B[1], omd[1] * k[1]);
        B[2] = fmaf(d[2], B[2], omd[2] * k[2]);
        B[3] = fmaf(d[3], B[3], omd[3] * k[3]);
    }
    Blds[w][lane] = B;
    __syncthreads();
    f32x4 A = d * d; A = A * A; A = A * A; A = A * A;
    f32x4 S = (f32x4)0.0f;
    for (int wp = 0; wp < w; ++wp) {
        const f32x4 Bp = Blds[wp][lane];
        S[0] = fmaf(A[0], S[0], Bp[0]);
        S[1] = fmaf(A[1], S[1], Bp[1]);
        S[2] = fmaf(A[2], S[2], Bp[2]);
        S[3] = fmaf(A[3], S[3], Bp[3]);
    }
    #pragma unroll
    for (int j = 0; j < T_DIM / NW; ++j) {
        f32x4 k  = kp[(size_t)j * CH4];
        f32x4 qq = qp[(size_t)j * CH4];
        S[0] = fmaf(d[0], S[0], omd[0] * k[0]);
        S[1] = fmaf(d[1], S[1], omd[1] * k[1]);
        S[2] = fmaf(d[2], S[2], omd[2] * k[2]);
        S[3] = fmaf(d[3], S[3], omd[3] * k[3]);
        f32x4 o = qq * S;
        __builtin_nontemporal_store(o, op + (size_t)j * CH4);
    }
}

extern "C" void kernel_launch(void* const* d_in, const int* in_sizes, int n_in,
                              void* d_out, int out_size, void* d_ws, size_t ws_size,
                              hipStream_t stream) {
    const f32x4* q     = (const f32x4*)d_in[0];
    const f32x4* kv    = (const f32x4*)d_in[1];
    const float* decay = (const float*)d_in[2];
    f32x4* out = (f32x4*)d_out;

    const size_t ws_need = (size_t)NC * CH4 * sizeof(f32x4);   // 6.55 MB
    if (d_ws != nullptr && ws_size >= ws_need) {
        f32x4* ws = (f32x4*)d_ws;
        sss_p1<<<NC * BPC, THR, 0, stream>>>(kv, decay, ws);
        sss_p2<<<NC * BPC, THR, 0, stream>>>(q, kv, decay, ws, out);
    } else {
        sss_scan_v7<<<CH4 / 64, NW * 64, 0, stream>>>(q, kv, decay, out);
    }
}